// Round 12
// baseline (1701.975 us; speedup 1.0000x reference)
//
#include <hip/hip_runtime.h>

#define I_SZ 256
#define H_SZ 512
#define O_SZ 256
#define B_SZ 4096
#define S_SZ 50
#define T_SZ 20
#define G4H  2048
#define BH   ((size_t)B_SZ * H_SZ)
#define NB   512                 // persistent grid: 2 blocks/CU x 256 CUs

#define PAD 72    // k_fc only
#define PAD_H 36  // epilogue h repack stride (halves)

typedef _Float16 half8 __attribute__((ext_vector_type(8)));
typedef float f32x4 __attribute__((ext_vector_type(4)));

__device__ __forceinline__ float sigm(float x) {
    return 1.0f / (1.0f + __expf(-x));
}
__device__ __forceinline__ float tanh_fast(float x) {
    float e = __expf(2.0f * x);
    return 1.0f - 2.0f / (e + 1.0f);
}

// async global->LDS, 16B/lane, linear LDS dest, cached (L1+L2)
#define GLDS(gp, lp) __builtin_amdgcn_global_load_lds(                      \
    (const __attribute__((address_space(1))) void*)(gp),                    \
    (__attribute__((address_space(3))) void*)(lp), 16, 0, 0)

#define MEMFENCE asm volatile("" ::: "memory")

// ---------------- one-time prep kernels ----------------
__global__ void k_zeroN(unsigned* p, int n) {
    int i = blockIdx.x * blockDim.x + threadIdx.x;
    if (i < n) p[i] = 0u;
}

__global__ void k_cvt(const float* __restrict__ src, _Float16* __restrict__ dst, int n) {
    int i = blockIdx.x * blockDim.x + threadIdx.x;
    if (i < n) dst[i] = (_Float16)src[i];
}

__global__ void k_bias_combine(const float* __restrict__ a, const float* __restrict__ b,
                               float* __restrict__ dst, int n) {
    int i = blockIdx.x * blockDim.x + threadIdx.x;
    if (i < n) dst[i] = a[i] + b[i];
}

// x [B][S][I] fp32 -> xT [S][B][I] fp16
__global__ __launch_bounds__(256) void k_cvt_x(const float* __restrict__ x,
                                               _Float16* __restrict__ xT) {
    size_t idx = ((size_t)blockIdx.x * 256 + threadIdx.x) * 8;
    int i = (int)(idx & 255);
    int s = (int)((idx >> 8) % S_SZ);
    size_t b = idx / (256 * S_SZ);
    float4 v0 = *(const float4*)(x + idx);
    float4 v1 = *(const float4*)(x + idx + 4);
    half8 hv;
    hv[0] = (_Float16)v0.x; hv[1] = (_Float16)v0.y;
    hv[2] = (_Float16)v0.z; hv[3] = (_Float16)v0.w;
    hv[4] = (_Float16)v1.x; hv[5] = (_Float16)v1.y;
    hv[6] = (_Float16)v1.z; hv[7] = (_Float16)v1.w;
    *(half8*)(xT + (((size_t)s * B_SZ + b) * I_SZ + i)) = hv;
}

// Wenc[r][0:256]=eWih[r], [256:768]=eWhh[r]  (fp16)
__global__ void k_wenc(const float* __restrict__ eWih, const float* __restrict__ eWhh,
                       _Float16* __restrict__ Wenc) {
    int idx = blockIdx.x * blockDim.x + threadIdx.x;
    int r = idx / 768, col = idx % 768;
    float v = (col < 256) ? eWih[(size_t)r * 256 + col] : eWhh[(size_t)r * 512 + col - 256];
    Wenc[idx] = (_Float16)v;
}

// Wd[r,k] = dWhh[r,k] + sum_o dWih[r,o] * fcW[o,k]
__global__ __launch_bounds__(256) void k_wd(
    const float* __restrict__ dWhh, const float* __restrict__ dWih,
    const float* __restrict__ fcW, _Float16* __restrict__ Wd)
{
    __shared__ float sA[8][256];
    const int tid = threadIdx.x;
    const int r0 = blockIdx.x * 8;
    {
        int linear = tid * 8;
        int row = linear >> 8, col = linear & 255;
        const float4* p = (const float4*)(dWih + (size_t)(r0 + row) * 256 + col);
        float4 v0 = p[0], v1 = p[1];
        *(float4*)&sA[row][col]     = v0;
        *(float4*)&sA[row][col + 4] = v1;
    }
    __syncthreads();
    float acc[8][2] = {};
    const int k = tid;
    for (int i = 0; i < 256; ++i) {
        float w0 = fcW[(size_t)i * 512 + k];
        float w1 = fcW[(size_t)i * 512 + k + 256];
        #pragma unroll
        for (int rr = 0; rr < 8; ++rr) {
            float a = sA[rr][i];
            acc[rr][0] += a * w0;
            acc[rr][1] += a * w1;
        }
    }
    #pragma unroll
    for (int rr = 0; rr < 8; ++rr) {
        size_t base = (size_t)(r0 + rr) * 512;
        Wd[base + k]       = (_Float16)(dWhh[base + k]       + acc[rr][0]);
        Wd[base + k + 256] = (_Float16)(dWhh[base + k + 256] + acc[rr][1]);
    }
}

// bd[r] = db[r] + sum_o dWih[r,o] * fcb[o]
__global__ __launch_bounds__(256) void k_bd(
    const float* __restrict__ dWih, const float* __restrict__ fcb,
    const float* __restrict__ db, float* __restrict__ bd)
{
    __shared__ float sf[256];
    const int tid = threadIdx.x;
    sf[tid] = fcb[tid];
    __syncthreads();
    int r = blockIdx.x * 256 + tid;
    float acc = db[r];
    const float* row = dWih + (size_t)r * 256;
    for (int o = 0; o < 256; o += 4) {
        float4 v = *(const float4*)(row + o);
        acc += v.x * sf[o] + v.y * sf[o + 1] + v.z * sf[o + 2] + v.w * sf[o + 3];
    }
    bd[r] = acc;
}

// ---------------- persistent whole-recurrence kernel ----------------
// Round-11 structure + (1) ONE barrier per iteration ([vmcnt][barrier][issue]
// [compute] -- issue-after-barrier makes the 2nd barrier redundant),
// (2) cross-step prefetch of A(0)/B(0) issued after the epilogue's sc-stores
// (in-order vmcnt: vmcnt(P) retires exactly the stores, prefetch stays in
// flight through arrive/wait), (3) dedicated hsm buffer (74.75KB total, the
// round-10-proven 2-blocks/CU envelope).
__global__ __launch_bounds__(256, 2) void k_lstm_all(
    const _Float16* __restrict__ xT,     // [S][B][256] fp16
    const _Float16* __restrict__ Wenc,   // [2048][768]
    const _Float16* __restrict__ dWhh_h, // [2048][512]
    const _Float16* __restrict__ Wd,     // [2048][512]
    const float* __restrict__ eb, const float* __restrict__ db,
    const float* __restrict__ bd,
    _Float16* __restrict__ henc,         // [49][B][512] unique slabs
    _Float16* __restrict__ hseq,         // [21][B][512]
    unsigned* __restrict__ bar)          // 32 counters, 16 uints apart
{
    __shared__ _Float16 lds[2][2][128 * 64];   // 64 KB (A,B double buffers)
    __shared__ _Float16 hsm[128 * PAD_H];      // 9 KB dedicated repack

    const int tid = threadIdx.x;
    // 2-D placement (validated round 11): W slice per XCD stays L2-resident.
    const int xcd = blockIdx.x & 7, slot = blockIdx.x >> 3;
    const int mb = (xcd >> 1) * 8 + (slot >> 3);
    const int jb = (xcd & 1) * 8 + (slot & 7);
    const int m0 = mb * 128, j0 = jb * 32;
    unsigned* grp = bar + mb * 16;

    const int wv = tid >> 6, lane = tid & 63, lrow = lane & 15, lk8 = (lane >> 4) * 8;
    const int wm = wv >> 1, wn = wv & 1;

    // ---- staging geometry: precomputed per-q pointers ----
    const int colb  = (lane & 7) * 16;
    const int scolh = (colb ^ (((lane >> 3) & 7) << 4)) >> 1;
    const _Float16* wEncQ[4]; const _Float16* wD0Q[4]; const _Float16* wDQ[4];
    const _Float16* xQ[4];
    unsigned aOffQ[4];
    int ldsQ[4];
    #pragma unroll
    for (int q = 0; q < 4; ++q) {
        int r = q * 32 + wv * 8 + (lane >> 3);
        int grow = ((r >> 4) & 3) * H_SZ + j0 + (r >> 6) * 16 + (r & 15);
        wEncQ[q] = Wenc   + (size_t)grow * 768 + scolh;
        wD0Q[q]  = dWhh_h + (size_t)grow * 512 + scolh;
        wDQ[q]   = Wd     + (size_t)grow * 512 + scolh;
        xQ[q]    = xT + (size_t)(m0 + r) * I_SZ + scolh;
        aOffQ[q] = (unsigned)((m0 + r) * H_SZ) + scolh;
        ldsQ[q]  = (q * 256 + wv * 64) * 8;
    }

    float ebj[4], dbj[4], bdj[4];
    #pragma unroll
    for (int nf = 0; nf < 4; ++nf) {
        int col = nf * H_SZ + j0 + wn * 16 + lrow;
        ebj[nf] = eb[col]; dbj[nf] = db[col]; bdj[nf] = bd[col];
    }

    float creg[4][4];

    auto wait_group = [&](unsigned target) {
        MEMFENCE;
        if (tid == 0) {
            while (__hip_atomic_load(grp, __ATOMIC_RELAXED, __HIP_MEMORY_SCOPE_AGENT) < target)
                __builtin_amdgcn_s_sleep(1);
        }
        __builtin_amdgcn_s_barrier();
        MEMFENCE;
    };

    auto compute = [&](int buf, f32x4 (&acc)[4][4]) {
        #pragma unroll
        for (int kc = 0; kc < 2; ++kc) {
            const int sc = (((kc * 32 + lk8) * 2) ^ ((lrow & 7) << 4)) >> 1;
            half8 a[4], b[4];
            #pragma unroll
            for (int mf = 0; mf < 4; ++mf)
                a[mf] = *(const half8*)&lds[buf][0][(wm * 64 + mf * 16 + lrow) * 64 + sc];
            #pragma unroll
            for (int nf = 0; nf < 4; ++nf)
                b[nf] = *(const half8*)&lds[buf][1][(wn * 64 + nf * 16 + lrow) * 64 + sc];
            #pragma unroll
            for (int mf = 0; mf < 4; ++mf)
                #pragma unroll
                for (int nf = 0; nf < 4; ++nf)
                    acc[mf][nf] = __builtin_amdgcn_mfma_f32_16x16x32_f16(a[mf], b[nf], acc[mf][nf], 0, 0, 0);
        }
    };

    // Epilogue: gates+cell update -> hsm -> coalesced sc-stores -> cross-step
    // prefetch (pfA may be null) -> vmcnt(P) retires exactly the stores ->
    // barrier -> tid0 signal (if sig).
    auto epilogue = [&](f32x4 (&acc)[4][4], const float (&bj)[4], _Float16* hout,
                        bool first, const _Float16* pfA, size_t pfAoff,
                        const _Float16* const* pfBq, bool sig) {
        MEMFENCE;
        const int lc = wn * 16 + lrow;
        #pragma unroll
        for (int mf = 0; mf < 4; ++mf)
            #pragma unroll
            for (int r = 0; r < 4; ++r) {
                int lr = wm * 64 + mf * 16 + (lane >> 4) * 4 + r;
                float gi = acc[mf][0][r] + bj[0];
                float gf = acc[mf][1][r] + bj[1];
                float gg = acc[mf][2][r] + bj[2];
                float go = acc[mf][3][r] + bj[3];
                float cold = first ? 0.0f : creg[mf][r];
                float cn = sigm(gf) * cold + sigm(gi) * tanh_fast(gg);
                creg[mf][r] = cn;
                hsm[lr * PAD_H + lc] = (_Float16)(sigm(go) * tanh_fast(cn));
            }
        asm volatile("s_waitcnt lgkmcnt(0)" ::: "memory");
        __builtin_amdgcn_s_barrier();
        MEMFENCE;
        {
            int rr = tid >> 3, k = tid & 7;   // 8 lanes/row: full 64B lines/instr
            #pragma unroll
            for (int q = 0; q < 4; ++q) {
                int r = rr + q * 32;
                unsigned long long v = *(const unsigned long long*)&hsm[r * PAD_H + k * 4];
                unsigned long long* dst =
                    (unsigned long long*)(hout + (size_t)(m0 + r) * H_SZ + j0) + k;
                __hip_atomic_store(dst, v, __ATOMIC_RELAXED, __HIP_MEMORY_SCOPE_AGENT);
            }
        }
        // cross-step prefetch AFTER the stores (stores retire first, in-order)
        int pf = 0;
        if (pfBq) {
            #pragma unroll
            for (int q = 0; q < 4; ++q) GLDS(pfBq[q], &lds[0][1][ldsQ[q]]);
            pf += 4;
        }
        if (pfA) {
            #pragma unroll
            for (int q = 0; q < 4; ++q) GLDS(pfA + pfAoff + (xQ[q] - xT), &lds[0][0][ldsQ[q]]);
            pf += 4;
        }
        if (pf == 8)      { asm volatile("s_waitcnt vmcnt(8)" ::: "memory"); }
        else if (pf == 4) { asm volatile("s_waitcnt vmcnt(4)" ::: "memory"); }
        else              { asm volatile("s_waitcnt vmcnt(0)" ::: "memory"); }
        __builtin_amdgcn_s_barrier();
        MEMFENCE;
        if (sig && tid == 0)
            __hip_atomic_fetch_add(grp, 1u, __ATOMIC_RELAXED, __HIP_MEMORY_SCOPE_AGENT);
    };

    // ================= encoder step 0 (x only, 4 tiles) =================
    {
        f32x4 acc[4][4] = {};
        #pragma unroll
        for (int q = 0; q < 4; ++q) { GLDS(xQ[q], &lds[0][0][ldsQ[q]]); GLDS(wEncQ[q], &lds[0][1][ldsQ[q]]); }
        #pragma unroll
        for (int it = 0; it < 4; ++it) {
            asm volatile("s_waitcnt vmcnt(0)" ::: "memory");
            __builtin_amdgcn_s_barrier(); MEMFENCE;
            if (it + 1 < 4) {
                #pragma unroll
                for (int q = 0; q < 4; ++q) {
                    GLDS(xQ[q] + (it + 1) * 64, &lds[(it + 1) & 1][0][ldsQ[q]]);
                    GLDS(wEncQ[q] + (it + 1) * 64, &lds[(it + 1) & 1][1][ldsQ[q]]);
                }
            }
            compute(it & 1, acc); MEMFENCE;
        }
        epilogue(acc, ebj, henc, true, xT, (size_t)1 * B_SZ * I_SZ, wEncQ, true);
    }

    // ================= encoder steps 1..49 (12 tiles) =================
    for (int s = 1; s < S_SZ; ++s) {
        const size_t xoff = (size_t)s * B_SZ * I_SZ;
        const _Float16* hin = henc + (size_t)(s - 1) * BH;
        _Float16* hout = (s == S_SZ - 1) ? hseq : henc + (size_t)s * BH;
        f32x4 acc[4][4] = {};
        // A(0)/B(0) already in flight (cross-step prefetch)
        #pragma unroll
        for (int it = 0; it < 12; ++it) {
            asm volatile("s_waitcnt vmcnt(0)" ::: "memory");
            if (it == 3) { wait_group((unsigned)s * 16u); }
            else         { __builtin_amdgcn_s_barrier(); MEMFENCE; }
            if (it + 1 < 12) {
                #pragma unroll
                for (int q = 0; q < 4; ++q) {
                    if (it + 1 < 4) GLDS(xQ[q] + xoff + (it + 1) * 64, &lds[(it + 1) & 1][0][ldsQ[q]]);
                    else            GLDS(hin + aOffQ[q] + (it - 3) * 64, &lds[(it + 1) & 1][0][ldsQ[q]]);
                    GLDS(wEncQ[q] + (it + 1) * 64, &lds[(it + 1) & 1][1][ldsQ[q]]);
                }
            }
            compute(it & 1, acc); MEMFENCE;
        }
        if (s < S_SZ - 1)
            epilogue(acc, ebj, hout, false, xT, (size_t)(s + 1) * B_SZ * I_SZ, wEncQ, true);
        else
            epilogue(acc, ebj, hout, false, nullptr, 0, wD0Q, true);
    }

    // ================= decoder steps 0..19 (8 tiles) =================
    for (int t = 0; t < T_SZ; ++t) {
        const _Float16* hin = hseq + (size_t)t * BH;
        _Float16* hout = hseq + (size_t)(t + 1) * BH;
        const _Float16* wq[4];
        float bj[4];
        #pragma unroll
        for (int q = 0; q < 4; ++q) wq[q] = t ? wDQ[q] : wD0Q[q];
        #pragma unroll
        for (int nf = 0; nf < 4; ++nf) bj[nf] = t ? bdj[nf] : dbj[nf];

        wait_group((unsigned)(S_SZ + t) * 16u);     // B(0) prefetched, flying
        f32x4 acc[4][4] = {};
        #pragma unroll
        for (int q = 0; q < 4; ++q) GLDS(hin + aOffQ[q], &lds[0][0][ldsQ[q]]);
        #pragma unroll
        for (int it = 0; it < 8; ++it) {
            asm volatile("s_waitcnt vmcnt(0)" ::: "memory");
            __builtin_amdgcn_s_barrier(); MEMFENCE;
            if (it + 1 < 8) {
                #pragma unroll
                for (int q = 0; q < 4; ++q) {
                    GLDS(hin + aOffQ[q] + (it + 1) * 64, &lds[(it + 1) & 1][0][ldsQ[q]]);
                    GLDS(wq[q] + (it + 1) * 64, &lds[(it + 1) & 1][1][ldsQ[q]]);
                }
            }
            compute(it & 1, acc); MEMFENCE;
        }
        if (t < T_SZ - 1)
            epilogue(acc, bj, hout, false, nullptr, 0, wDQ, true);
        else
            epilogue(acc, bj, hout, false, nullptr, 0, nullptr, false);
    }
}

// ---------------- batched final FC over all decoder h's ----------------
__global__ __launch_bounds__(256) void k_fc(
    const _Float16* __restrict__ hseq1,  // [T][B][512]
    const _Float16* __restrict__ W,      // fcW fp16 [256][512]
    const float* __restrict__ bias,      // [256]
    float* __restrict__ out)
{
    __shared__ _Float16 Asm[128][PAD];
    __shared__ _Float16 Bsm[128][PAD];

    const int tid = threadIdx.x;
    const int m0 = blockIdx.x * 128;
    const int t  = blockIdx.y;
    const int n0 = blockIdx.z * 128;
    const int wv = tid >> 6, lane = tid & 63, lrow = lane & 15, lk = (lane >> 4) * 8;
    const int wm = wv >> 1, wn = wv & 1;

    f32x4 acc[4][4] = {};

    const int srow = tid >> 3, skc = (tid & 7) * 8;
    const _Float16* A = hseq1 + (size_t)t * BH;

    for (int k0 = 0; k0 < H_SZ; k0 += 64) {
        __syncthreads();
        #pragma unroll
        for (int q = 0; q < 4; ++q) {
            int r = srow + q * 32;
            *(half8*)&Asm[r][skc] = *(const half8*)(A + (size_t)(m0 + r) * H_SZ + k0 + skc);
        }
        #pragma unroll
        for (int q = 0; q < 4; ++q) {
            int rr = srow + q * 32;
            *(half8*)&Bsm[rr][skc] = *(const half8*)(W + (size_t)(n0 + rr) * H_SZ + k0 + skc);
        }
        __syncthreads();
        #pragma unroll
        for (int kc = 0; kc < 64; kc += 32) {
            half8 a[4], b[4];
            #pragma unroll
            for (int mf = 0; mf < 4; ++mf) a[mf] = *(const half8*)&Asm[wm * 64 + mf * 16 + lrow][kc + lk];
            #pragma unroll
            for (int nf = 0; nf < 4; ++nf) b[nf] = *(const half8*)&Bsm[wn * 64 + nf * 16 + lrow][kc + lk];
            #pragma unroll
            for (int mf = 0; mf < 4; ++mf)
                #pragma unroll
                for (int nf = 0; nf < 4; ++nf)
                    acc[mf][nf] = __builtin_amdgcn_mfma_f32_16x16x32_f16(a[mf], b[nf], acc[mf][nf], 0, 0, 0);
        }
    }

    #pragma unroll
    for (int mf = 0; mf < 4; ++mf)
        #pragma unroll
        for (int nf = 0; nf < 4; ++nf) {
            int o = n0 + wn * 64 + nf * 16 + lrow;
            float bv = bias[o];
            #pragma unroll
            for (int r = 0; r < 4; ++r) {
                int m = m0 + wm * 64 + mf * 16 + (lane >> 4) * 4 + r;
                out[(size_t)m * (T_SZ * O_SZ) + (size_t)t * O_SZ + o] = acc[mf][nf][r] + bv;
            }
        }
}

extern "C" void kernel_launch(void* const* d_in, const int* in_sizes, int n_in,
                              void* d_out, int out_size, void* d_ws, size_t ws_size,
                              hipStream_t stream) {
    (void)in_sizes; (void)n_in; (void)out_size; (void)ws_size;

    const float* x    = (const float*)d_in[0];
    const float* eWih = (const float*)d_in[1];
    const float* eWhh = (const float*)d_in[2];
    const float* ebih = (const float*)d_in[3];
    const float* ebhh = (const float*)d_in[4];
    const float* dWih = (const float*)d_in[5];
    const float* dWhh = (const float*)d_in[6];
    const float* dbih = (const float*)d_in[7];
    const float* dbhh = (const float*)d_in[8];
    const float* fcW  = (const float*)d_in[9];
    const float* fcb  = (const float*)d_in[10];
    float* out = (float*)d_out;
    char* ws = (char*)d_ws;

    size_t off = 0;
    auto alloc = [&](size_t bytes) -> void* {
        void* p = ws + off;
        off += (bytes + 255) & ~(size_t)255;
        return p;
    };
    _Float16* xT     = (_Float16*)alloc((size_t)S_SZ * B_SZ * I_SZ * 2);
    _Float16* Wenc   = (_Float16*)alloc((size_t)G4H * (I_SZ + H_SZ) * 2);
    _Float16* dWhh_h = (_Float16*)alloc((size_t)G4H * H_SZ * 2);
    _Float16* Wd     = (_Float16*)alloc((size_t)G4H * H_SZ * 2);
    _Float16* fcW_h  = (_Float16*)alloc((size_t)O_SZ * H_SZ * 2);
    float*    eb     = (float*)alloc(G4H * 4);
    float*    db     = (float*)alloc(G4H * 4);
    float*    bd     = (float*)alloc(G4H * 4);
    _Float16* henc   = (_Float16*)alloc((size_t)(S_SZ - 1) * BH * 2);   // 49 slabs
    _Float16* hseq   = (_Float16*)alloc((size_t)(T_SZ + 1) * BH * 2);   // 21 slabs
    unsigned* bar    = (unsigned*)alloc(32 * 16 * 4);

    const int nWhh = G4H * H_SZ;
    const int nFc  = O_SZ * H_SZ;
    const size_t nX = (size_t)B_SZ * S_SZ * I_SZ;

    k_zeroN<<<2, 256, 0, stream>>>(bar, 32 * 16);
    k_cvt_x<<<(int)(nX / 8 / 256), 256, 0, stream>>>(x, xT);
    k_wenc<<<(G4H * 768) / 256, 256, 0, stream>>>(eWih, eWhh, Wenc);
    k_cvt<<<(nWhh + 255) / 256, 256, 0, stream>>>(dWhh, dWhh_h, nWhh);
    k_cvt<<<(nFc + 255) / 256, 256, 0, stream>>>(fcW, fcW_h, nFc);
    k_bias_combine<<<8, 256, 0, stream>>>(ebih, ebhh, eb, G4H);
    k_bias_combine<<<8, 256, 0, stream>>>(dbih, dbhh, db, G4H);
    k_wd<<<256, 256, 0, stream>>>(dWhh, dWih, fcW, Wd);
    k_bd<<<8, 256, 0, stream>>>(dWih, fcb, db, bd);

    k_lstm_all<<<NB, 256, 0, stream>>>(xT, Wenc, dWhh_h, Wd, eb, db, bd,
                                       henc, hseq, bar);

    k_fc<<<dim3(B_SZ / 128, T_SZ, O_SZ / 128), 256, 0, stream>>>(
        hseq + BH, fcW_h, fcb, out);
}

// Round 14
// 1344.522 us; speedup vs baseline: 1.2659x; 1.2659x over previous
//
#include <hip/hip_runtime.h>

#define I_SZ 256
#define H_SZ 512
#define O_SZ 256
#define B_SZ 4096
#define S_SZ 50
#define T_SZ 20
#define G4H  2048
#define BH   ((size_t)B_SZ * H_SZ)
#define NB   512                 // persistent grid: 2 blocks/CU x 256 CUs

#define PAD 72    // k_fc only
#define PAD_H 36  // epilogue h repack stride (halves)

typedef _Float16 half8 __attribute__((ext_vector_type(8)));
typedef float f32x4 __attribute__((ext_vector_type(4)));

__device__ __forceinline__ float sigm(float x) {
    return 1.0f / (1.0f + __expf(-x));
}
__device__ __forceinline__ float tanh_fast(float x) {
    float e = __expf(2.0f * x);
    return 1.0f - 2.0f / (e + 1.0f);
}

// async global->LDS, 16B/lane, linear LDS dest, cached (L1+L2)
#define GLDS(gp, lp) __builtin_amdgcn_global_load_lds(                      \
    (const __attribute__((address_space(1))) void*)(gp),                    \
    (__attribute__((address_space(3))) void*)(lp), 16, 0, 0)

#define MEMFENCE asm volatile("" ::: "memory")

// ---------------- one-time prep kernels ----------------
// fused small prep: bar zero, eb/db bias combine, bd fold, fcW cvt
__global__ __launch_bounds__(256) void k_prep_small(
    unsigned* __restrict__ bar,
    const float* __restrict__ ebih, const float* __restrict__ ebhh,
    const float* __restrict__ dbih, const float* __restrict__ dbhh,
    const float* __restrict__ dWih, const float* __restrict__ fcb,
    const float* __restrict__ fcW, float* __restrict__ eb,
    float* __restrict__ db, float* __restrict__ bd,
    _Float16* __restrict__ fcW_h)
{
    const int tid = threadIdx.x;
    const int b = blockIdx.x;
    if (b < 8) {
        int r = b * 256 + tid;
        eb[r] = ebih[r] + ebhh[r];
        float dbv = dbih[r] + dbhh[r];
        db[r] = dbv;
        __shared__ float sf[256];
        sf[tid] = fcb[tid];
        __syncthreads();
        float acc = dbv;
        const float* row = dWih + (size_t)r * 256;
        for (int o = 0; o < 256; o += 4) {
            float4 v = *(const float4*)(row + o);
            acc += v.x * sf[o] + v.y * sf[o + 1] + v.z * sf[o + 2] + v.w * sf[o + 3];
        }
        bd[r] = acc;
        if (b == 0) {
            for (int i = tid; i < 512; i += 256) bar[i] = 0u;   // 32 groups x 16 pad
        }
    } else {
        int i = (b - 8) * 256 + tid;
        if (i < O_SZ * H_SZ) fcW_h[i] = (_Float16)fcW[i];
    }
}

__global__ void k_cvt(const float* __restrict__ src, _Float16* __restrict__ dst, int n) {
    int i = blockIdx.x * blockDim.x + threadIdx.x;
    if (i < n) dst[i] = (_Float16)src[i];
}

// x [B][S][I] fp32 -> xT [S][B][I] fp16
__global__ __launch_bounds__(256) void k_cvt_x(const float* __restrict__ x,
                                               _Float16* __restrict__ xT) {
    size_t idx = ((size_t)blockIdx.x * 256 + threadIdx.x) * 8;
    int i = (int)(idx & 255);
    int s = (int)((idx >> 8) % S_SZ);
    size_t b = idx / (256 * S_SZ);
    float4 v0 = *(const float4*)(x + idx);
    float4 v1 = *(const float4*)(x + idx + 4);
    half8 hv;
    hv[0] = (_Float16)v0.x; hv[1] = (_Float16)v0.y;
    hv[2] = (_Float16)v0.z; hv[3] = (_Float16)v0.w;
    hv[4] = (_Float16)v1.x; hv[5] = (_Float16)v1.y;
    hv[6] = (_Float16)v1.z; hv[7] = (_Float16)v1.w;
    *(half8*)(xT + (((size_t)s * B_SZ + b) * I_SZ + i)) = hv;
}

// Wenc[r][0:256]=eWih[r], [256:768]=eWhh[r]  (fp16)
__global__ void k_wenc(const float* __restrict__ eWih, const float* __restrict__ eWhh,
                       _Float16* __restrict__ Wenc) {
    int idx = blockIdx.x * blockDim.x + threadIdx.x;
    int r = idx / 768, col = idx % 768;
    float v = (col < 256) ? eWih[(size_t)r * 256 + col] : eWhh[(size_t)r * 512 + col - 256];
    Wenc[idx] = (_Float16)v;
}

// Wd[r,k] = dWhh[r,k] + sum_o dWih[r,o] * fcW[o,k]
__global__ __launch_bounds__(256) void k_wd(
    const float* __restrict__ dWhh, const float* __restrict__ dWih,
    const float* __restrict__ fcW, _Float16* __restrict__ Wd)
{
    __shared__ float sA[8][256];
    const int tid = threadIdx.x;
    const int r0 = blockIdx.x * 8;
    {
        int linear = tid * 8;
        int row = linear >> 8, col = linear & 255;
        const float4* p = (const float4*)(dWih + (size_t)(r0 + row) * 256 + col);
        float4 v0 = p[0], v1 = p[1];
        *(float4*)&sA[row][col]     = v0;
        *(float4*)&sA[row][col + 4] = v1;
    }
    __syncthreads();
    float acc[8][2] = {};
    const int k = tid;
    for (int i = 0; i < 256; ++i) {
        float w0 = fcW[(size_t)i * 512 + k];
        float w1 = fcW[(size_t)i * 512 + k + 256];
        #pragma unroll
        for (int rr = 0; rr < 8; ++rr) {
            float a = sA[rr][i];
            acc[rr][0] += a * w0;
            acc[rr][1] += a * w1;
        }
    }
    #pragma unroll
    for (int rr = 0; rr < 8; ++rr) {
        size_t base = (size_t)(r0 + rr) * 512;
        Wd[base + k]       = (_Float16)(dWhh[base + k]       + acc[rr][0]);
        Wd[base + k + 256] = (_Float16)(dWhh[base + k + 256] + acc[rr][1]);
    }
}

// ---------------- persistent whole-recurrence kernel ----------------
// Round-11 structure (validated best): GLDS staging, 2-buf double buffer,
// counted vmcnt(8), 2 barriers/iter, unique h slab per step, sc write-through
// h stores, relaxed group counters, 2-D XCD placement (W slice L2-resident).
// Round-14 deltas (race-free): decoder pre-stages ONLY B(0) before the group
// wait (lds[0][1] untouched by anything until compute(0) reads it); in-loop
// staging is the validated round-11 1-ahead ring; setprio around MFMA (T5).
__global__ __launch_bounds__(256, 2) void k_lstm_all(
    const _Float16* __restrict__ xT,     // [S][B][256] fp16
    const _Float16* __restrict__ Wenc,   // [2048][768]
    const _Float16* __restrict__ dWhh_h, // [2048][512]
    const _Float16* __restrict__ Wd,     // [2048][512]
    const float* __restrict__ eb, const float* __restrict__ db,
    const float* __restrict__ bd,
    _Float16* __restrict__ henc,         // [49][B][512] unique slabs
    _Float16* __restrict__ hseq,         // [21][B][512]
    unsigned* __restrict__ bar)          // 32 counters, 16 uints apart
{
    __shared__ _Float16 lds[2][2][128 * 64];   // 64 KB

    const int tid = threadIdx.x;
    // 2-D placement (validated round 11): W slice per XCD stays L2-resident.
    const int xcd = blockIdx.x & 7, slot = blockIdx.x >> 3;
    const int mb = (xcd >> 1) * 8 + (slot >> 3);
    const int jb = (xcd & 1) * 8 + (slot & 7);
    const int m0 = mb * 128, j0 = jb * 32;
    unsigned* grp = bar + mb * 16;

    const int wv = tid >> 6, lane = tid & 63, lrow = lane & 15, lk8 = (lane >> 4) * 8;
    const int wm = wv >> 1, wn = wv & 1;

    // ---- staging geometry: precomputed per-q pointers ----
    const int colb  = (lane & 7) * 16;
    const int scolh = (colb ^ (((lane >> 3) & 7) << 4)) >> 1;
    const _Float16* wEncQ[4]; const _Float16* wD0Q[4]; const _Float16* wDQ[4];
    const _Float16* xQ[4];
    unsigned aOffQ[4];
    int ldsQ[4];
    #pragma unroll
    for (int q = 0; q < 4; ++q) {
        int r = q * 32 + wv * 8 + (lane >> 3);
        int grow = ((r >> 4) & 3) * H_SZ + j0 + (r >> 6) * 16 + (r & 15);
        wEncQ[q] = Wenc   + (size_t)grow * 768 + scolh;
        wD0Q[q]  = dWhh_h + (size_t)grow * 512 + scolh;
        wDQ[q]   = Wd     + (size_t)grow * 512 + scolh;
        xQ[q]    = xT + (size_t)(m0 + r) * I_SZ + scolh;
        aOffQ[q] = (unsigned)((m0 + r) * H_SZ) + scolh;
        ldsQ[q]  = (q * 256 + wv * 64) * 8;
    }

    float ebj[4], dbj[4], bdj[4];
    #pragma unroll
    for (int nf = 0; nf < 4; ++nf) {
        int col = nf * H_SZ + j0 + wn * 16 + lrow;
        ebj[nf] = eb[col]; dbj[nf] = db[col]; bdj[nf] = bd[col];
    }

    float creg[4][4];

    auto wait_group = [&](unsigned target) {
        MEMFENCE;
        if (tid == 0) {
            while (__hip_atomic_load(grp, __ATOMIC_RELAXED, __HIP_MEMORY_SCOPE_AGENT) < target)
                __builtin_amdgcn_s_sleep(1);
        }
        __builtin_amdgcn_s_barrier();
        MEMFENCE;
    };
    auto arrive = [&]() {
        __syncthreads();   // drains h sc-stores (vmcnt 0) before signaling
        if (tid == 0)
            __hip_atomic_fetch_add(grp, 1u, __ATOMIC_RELAXED, __HIP_MEMORY_SCOPE_AGENT);
    };

    auto compute = [&](int buf, f32x4 (&acc)[4][4]) {
        __builtin_amdgcn_s_setprio(1);
        #pragma unroll
        for (int kc = 0; kc < 2; ++kc) {
            const int sc = (((kc * 32 + lk8) * 2) ^ ((lrow & 7) << 4)) >> 1;
            half8 a[4], b[4];
            #pragma unroll
            for (int mf = 0; mf < 4; ++mf)
                a[mf] = *(const half8*)&lds[buf][0][(wm * 64 + mf * 16 + lrow) * 64 + sc];
            #pragma unroll
            for (int nf = 0; nf < 4; ++nf)
                b[nf] = *(const half8*)&lds[buf][1][(wn * 64 + nf * 16 + lrow) * 64 + sc];
            #pragma unroll
            for (int mf = 0; mf < 4; ++mf)
                #pragma unroll
                for (int nf = 0; nf < 4; ++nf)
                    acc[mf][nf] = __builtin_amdgcn_mfma_f32_16x16x32_f16(a[mf], b[nf], acc[mf][nf], 0, 0, 0);
        }
        __builtin_amdgcn_s_setprio(0);
    };

    auto epilogue = [&](f32x4 (&acc)[4][4], const float (&bj)[4], _Float16* hout, bool first) {
        _Float16* hsm = &lds[0][0][0];
        const int lc = wn * 16 + lrow;
        #pragma unroll
        for (int mf = 0; mf < 4; ++mf)
            #pragma unroll
            for (int r = 0; r < 4; ++r) {
                int lr = wm * 64 + mf * 16 + (lane >> 4) * 4 + r;
                float gi = acc[mf][0][r] + bj[0];
                float gf = acc[mf][1][r] + bj[1];
                float gg = acc[mf][2][r] + bj[2];
                float go = acc[mf][3][r] + bj[3];
                float cold = first ? 0.0f : creg[mf][r];
                float cn = sigm(gf) * cold + sigm(gi) * tanh_fast(gg);
                creg[mf][r] = cn;
                hsm[lr * PAD_H + lc] = (_Float16)(sigm(go) * tanh_fast(cn));
            }
        __syncthreads();
        int rr = tid >> 3, k = tid & 7;
        #pragma unroll
        for (int q = 0; q < 4; ++q) {
            int r = rr + q * 32;
            unsigned long long v = *(const unsigned long long*)&hsm[r * PAD_H + k * 4];
            unsigned long long* dst =
                (unsigned long long*)(hout + (size_t)(m0 + r) * H_SZ + j0) + k;
            __hip_atomic_store(dst, v, __ATOMIC_RELAXED, __HIP_MEMORY_SCOPE_AGENT);
        }
    };

    // ================= phase A: encoder step 0 (x only, 4 tiles) =================
    {
        f32x4 acc[4][4] = {};
        #pragma unroll
        for (int q = 0; q < 4; ++q) { GLDS(xQ[q], &lds[0][0][ldsQ[q]]); GLDS(wEncQ[q], &lds[0][1][ldsQ[q]]); }
        #pragma unroll
        for (int it = 0; it < 4; ++it) {
            if (it < 3) {
                #pragma unroll
                for (int q = 0; q < 4; ++q) {
                    GLDS(xQ[q] + (it + 1) * 64, &lds[(it + 1) & 1][0][ldsQ[q]]);
                    GLDS(wEncQ[q] + (it + 1) * 64, &lds[(it + 1) & 1][1][ldsQ[q]]);
                }
                asm volatile("s_waitcnt vmcnt(8)" ::: "memory");
            } else {
                asm volatile("s_waitcnt vmcnt(0)" ::: "memory");
            }
            __builtin_amdgcn_s_barrier(); MEMFENCE;
            compute(it & 1, acc);
            MEMFENCE; __builtin_amdgcn_s_barrier(); MEMFENCE;
        }
        epilogue(acc, ebj, henc, true);
        arrive();
    }

    // ================= phase B: encoder steps 1..49 (12 tiles) =================
    for (int s = 1; s < S_SZ; ++s) {
        const size_t xoff = (size_t)s * B_SZ * I_SZ;
        const _Float16* hin = henc + (size_t)(s - 1) * BH;
        _Float16* hout = (s == S_SZ - 1) ? hseq : henc + (size_t)s * BH;
        f32x4 acc[4][4] = {};
        #pragma unroll
        for (int q = 0; q < 4; ++q) { GLDS(xQ[q] + xoff, &lds[0][0][ldsQ[q]]); GLDS(wEncQ[q], &lds[0][1][ldsQ[q]]); }
        #pragma unroll
        for (int it = 0; it < 12; ++it) {
            if (it < 11) {
                if (it == 3) wait_group((unsigned)s * 16u);
                #pragma unroll
                for (int q = 0; q < 4; ++q) {
                    if (it + 1 < 4) GLDS(xQ[q] + xoff + (it + 1) * 64, &lds[(it + 1) & 1][0][ldsQ[q]]);
                    else            GLDS(hin + aOffQ[q] + (it - 3) * 64, &lds[(it + 1) & 1][0][ldsQ[q]]);
                    GLDS(wEncQ[q] + (it + 1) * 64, &lds[(it + 1) & 1][1][ldsQ[q]]);
                }
                asm volatile("s_waitcnt vmcnt(8)" ::: "memory");
            } else {
                asm volatile("s_waitcnt vmcnt(0)" ::: "memory");
            }
            __builtin_amdgcn_s_barrier(); MEMFENCE;
            compute(it & 1, acc);
            MEMFENCE; __builtin_amdgcn_s_barrier(); MEMFENCE;
        }
        epilogue(acc, ebj, hout, false);
        arrive();
    }

    // ================= phase C: decoder steps 0..19 (8 tiles) =================
    for (int t = 0; t < T_SZ; ++t) {
        const _Float16* hin = hseq + (size_t)t * BH;
        _Float16* hout = hseq + (size_t)(t + 1) * BH;
        const _Float16* wq[4];
        float bj[4];
        #pragma unroll
        for (int q = 0; q < 4; ++q) wq[q] = t ? wDQ[q] : wD0Q[q];
        #pragma unroll
        for (int nf = 0; nf < 4; ++nf) bj[nf] = t ? bdj[nf] : dbj[nf];

        // Pre-stage ONLY B(0) (h-independent) before the wait: lds[0][1] is
        // untouched by anything else until compute(0) reads it -> race-free.
        f32x4 acc[4][4] = {};
        #pragma unroll
        for (int q = 0; q < 4; ++q) { GLDS(wq[q], &lds[0][1][ldsQ[q]]); }
        wait_group((unsigned)(S_SZ + t) * 16u);
        #pragma unroll
        for (int q = 0; q < 4; ++q) { GLDS(hin + aOffQ[q], &lds[0][0][ldsQ[q]]); }
        #pragma unroll
        for (int it = 0; it < 8; ++it) {
            if (it < 7) {
                #pragma unroll
                for (int q = 0; q < 4; ++q) {
                    GLDS(hin + aOffQ[q] + (it + 1) * 64, &lds[(it + 1) & 1][0][ldsQ[q]]);
                    GLDS(wq[q] + (it + 1) * 64, &lds[(it + 1) & 1][1][ldsQ[q]]);
                }
                asm volatile("s_waitcnt vmcnt(8)" ::: "memory");
            } else {
                asm volatile("s_waitcnt vmcnt(0)" ::: "memory");
            }
            __builtin_amdgcn_s_barrier(); MEMFENCE;
            compute(it & 1, acc);
            MEMFENCE; __builtin_amdgcn_s_barrier(); MEMFENCE;
        }
        epilogue(acc, bj, hout, false);
        if (t != T_SZ - 1) arrive();
    }
}

// ---------------- batched final FC over all decoder h's ----------------
__global__ __launch_bounds__(256) void k_fc(
    const _Float16* __restrict__ hseq1,  // [T][B][512]
    const _Float16* __restrict__ W,      // fcW fp16 [256][512]
    const float* __restrict__ bias,      // [256]
    float* __restrict__ out)
{
    __shared__ _Float16 Asm[128][PAD];
    __shared__ _Float16 Bsm[128][PAD];

    const int tid = threadIdx.x;
    const int m0 = blockIdx.x * 128;
    const int t  = blockIdx.y;
    const int n0 = blockIdx.z * 128;
    const int wv = tid >> 6, lane = tid & 63, lrow = lane & 15, lk = (lane >> 4) * 8;
    const int wm = wv >> 1, wn = wv & 1;

    f32x4 acc[4][4] = {};

    const int srow = tid >> 3, skc = (tid & 7) * 8;
    const _Float16* A = hseq1 + (size_t)t * BH;

    for (int k0 = 0; k0 < H_SZ; k0 += 64) {
        __syncthreads();
        #pragma unroll
        for (int q = 0; q < 4; ++q) {
            int r = srow + q * 32;
            *(half8*)&Asm[r][skc] = *(const half8*)(A + (size_t)(m0 + r) * H_SZ + k0 + skc);
        }
        #pragma unroll
        for (int q = 0; q < 4; ++q) {
            int rr = srow + q * 32;
            *(half8*)&Bsm[rr][skc] = *(const half8*)(W + (size_t)(n0 + rr) * H_SZ + k0 + skc);
        }
        __syncthreads();
        #pragma unroll
        for (int kc = 0; kc < 64; kc += 32) {
            half8 a[4], b[4];
            #pragma unroll
            for (int mf = 0; mf < 4; ++mf) a[mf] = *(const half8*)&Asm[wm * 64 + mf * 16 + lrow][kc + lk];
            #pragma unroll
            for (int nf = 0; nf < 4; ++nf) b[nf] = *(const half8*)&Bsm[wn * 64 + nf * 16 + lrow][kc + lk];
            #pragma unroll
            for (int mf = 0; mf < 4; ++mf)
                #pragma unroll
                for (int nf = 0; nf < 4; ++nf)
                    acc[mf][nf] = __builtin_amdgcn_mfma_f32_16x16x32_f16(a[mf], b[nf], acc[mf][nf], 0, 0, 0);
        }
    }

    #pragma unroll
    for (int mf = 0; mf < 4; ++mf)
        #pragma unroll
        for (int nf = 0; nf < 4; ++nf) {
            int o = n0 + wn * 64 + nf * 16 + lrow;
            float bv = bias[o];
            #pragma unroll
            for (int r = 0; r < 4; ++r) {
                int m = m0 + wm * 64 + mf * 16 + (lane >> 4) * 4 + r;
                out[(size_t)m * (T_SZ * O_SZ) + (size_t)t * O_SZ + o] = acc[mf][nf][r] + bv;
            }
        }
}

extern "C" void kernel_launch(void* const* d_in, const int* in_sizes, int n_in,
                              void* d_out, int out_size, void* d_ws, size_t ws_size,
                              hipStream_t stream) {
    (void)in_sizes; (void)n_in; (void)out_size; (void)ws_size;

    const float* x    = (const float*)d_in[0];
    const float* eWih = (const float*)d_in[1];
    const float* eWhh = (const float*)d_in[2];
    const float* ebih = (const float*)d_in[3];
    const float* ebhh = (const float*)d_in[4];
    const float* dWih = (const float*)d_in[5];
    const float* dWhh = (const float*)d_in[6];
    const float* dbih = (const float*)d_in[7];
    const float* dbhh = (const float*)d_in[8];
    const float* fcW  = (const float*)d_in[9];
    const float* fcb  = (const float*)d_in[10];
    float* out = (float*)d_out;
    char* ws = (char*)d_ws;

    size_t off = 0;
    auto alloc = [&](size_t bytes) -> void* {
        void* p = ws + off;
        off += (bytes + 255) & ~(size_t)255;
        return p;
    };
    _Float16* xT     = (_Float16*)alloc((size_t)S_SZ * B_SZ * I_SZ * 2);
    _Float16* Wenc   = (_Float16*)alloc((size_t)G4H * (I_SZ + H_SZ) * 2);
    _Float16* dWhh_h = (_Float16*)alloc((size_t)G4H * H_SZ * 2);
    _Float16* Wd     = (_Float16*)alloc((size_t)G4H * H_SZ * 2);
    _Float16* fcW_h  = (_Float16*)alloc((size_t)O_SZ * H_SZ * 2);
    float*    eb     = (float*)alloc(G4H * 4);
    float*    db     = (float*)alloc(G4H * 4);
    float*    bd     = (float*)alloc(G4H * 4);
    _Float16* henc   = (_Float16*)alloc((size_t)(S_SZ - 1) * BH * 2);   // 49 slabs
    _Float16* hseq   = (_Float16*)alloc((size_t)(T_SZ + 1) * BH * 2);   // 21 slabs
    unsigned* bar    = (unsigned*)alloc(32 * 16 * 4);

    const int nWhh = G4H * H_SZ;
    const size_t nX = (size_t)B_SZ * S_SZ * I_SZ;

    k_prep_small<<<8 + (O_SZ * H_SZ + 255) / 256, 256, 0, stream>>>(
        bar, ebih, ebhh, dbih, dbhh, dWih, fcb, fcW, eb, db, bd, fcW_h);
    k_cvt_x<<<(int)(nX / 8 / 256), 256, 0, stream>>>(x, xT);
    k_wenc<<<(G4H * 768) / 256, 256, 0, stream>>>(eWih, eWhh, Wenc);
    k_cvt<<<(nWhh + 255) / 256, 256, 0, stream>>>(dWhh, dWhh_h, nWhh);
    k_wd<<<256, 256, 0, stream>>>(dWhh, dWih, fcW, Wd);

    k_lstm_all<<<NB, 256, 0, stream>>>(xT, Wenc, dWhh_h, Wd, eb, db, bd,
                                       henc, hseq, bar);

    k_fc<<<dim3(B_SZ / 128, T_SZ, O_SZ / 128), 256, 0, stream>>>(
        hseq + BH, fcW_h, fcb, out);
}

// Round 15
// 1283.831 us; speedup vs baseline: 1.3257x; 1.0473x over previous
//
#include <hip/hip_runtime.h>

#define I_SZ 256
#define H_SZ 512
#define O_SZ 256
#define B_SZ 4096
#define S_SZ 50
#define T_SZ 20
#define G4H  2048
#define BH   ((size_t)B_SZ * H_SZ)
#define NB   512                 // persistent grid: 2 blocks/CU x 256 CUs

#define PAD 72    // k_fc only
#define PAD_H 36  // epilogue h repack stride (halves)

typedef _Float16 half8 __attribute__((ext_vector_type(8)));
typedef float f32x4 __attribute__((ext_vector_type(4)));

__device__ __forceinline__ float sigm(float x) {
    return 1.0f / (1.0f + __expf(-x));
}
__device__ __forceinline__ float tanh_fast(float x) {
    float e = __expf(2.0f * x);
    return 1.0f - 2.0f / (e + 1.0f);
}

// async global->LDS, 16B/lane, linear LDS dest, cached (L1+L2)
#define GLDS(gp, lp) __builtin_amdgcn_global_load_lds(                      \
    (const __attribute__((address_space(1))) void*)(gp),                    \
    (__attribute__((address_space(3))) void*)(lp), 16, 0, 0)

#define MEMFENCE asm volatile("" ::: "memory")

// ---------------- one-time prep kernels ----------------
// fused small prep (validated r14): bar zero, eb/db bias combine, bd fold, fcW cvt
__global__ __launch_bounds__(256) void k_prep_small(
    unsigned* __restrict__ bar,
    const float* __restrict__ ebih, const float* __restrict__ ebhh,
    const float* __restrict__ dbih, const float* __restrict__ dbhh,
    const float* __restrict__ dWih, const float* __restrict__ fcb,
    const float* __restrict__ fcW, float* __restrict__ eb,
    float* __restrict__ db, float* __restrict__ bd,
    _Float16* __restrict__ fcW_h)
{
    const int tid = threadIdx.x;
    const int b = blockIdx.x;
    if (b < 8) {
        int r = b * 256 + tid;
        eb[r] = ebih[r] + ebhh[r];
        float dbv = dbih[r] + dbhh[r];
        db[r] = dbv;
        __shared__ float sf[256];
        sf[tid] = fcb[tid];
        __syncthreads();
        float acc = dbv;
        const float* row = dWih + (size_t)r * 256;
        for (int o = 0; o < 256; o += 4) {
            float4 v = *(const float4*)(row + o);
            acc += v.x * sf[o] + v.y * sf[o + 1] + v.z * sf[o + 2] + v.w * sf[o + 3];
        }
        bd[r] = acc;
        if (b == 0) {
            for (int i = tid; i < 512; i += 256) bar[i] = 0u;   // 32 groups x 16 pad
        }
    } else {
        int i = (b - 8) * 256 + tid;
        if (i < O_SZ * H_SZ) fcW_h[i] = (_Float16)fcW[i];
    }
}

__global__ void k_cvt(const float* __restrict__ src, _Float16* __restrict__ dst, int n) {
    int i = blockIdx.x * blockDim.x + threadIdx.x;
    if (i < n) dst[i] = (_Float16)src[i];
}

// x [B][S][I] fp32 -> xT [S][B][I] fp16
__global__ __launch_bounds__(256) void k_cvt_x(const float* __restrict__ x,
                                               _Float16* __restrict__ xT) {
    size_t idx = ((size_t)blockIdx.x * 256 + threadIdx.x) * 8;
    int i = (int)(idx & 255);
    int s = (int)((idx >> 8) % S_SZ);
    size_t b = idx / (256 * S_SZ);
    float4 v0 = *(const float4*)(x + idx);
    float4 v1 = *(const float4*)(x + idx + 4);
    half8 hv;
    hv[0] = (_Float16)v0.x; hv[1] = (_Float16)v0.y;
    hv[2] = (_Float16)v0.z; hv[3] = (_Float16)v0.w;
    hv[4] = (_Float16)v1.x; hv[5] = (_Float16)v1.y;
    hv[6] = (_Float16)v1.z; hv[7] = (_Float16)v1.w;
    *(half8*)(xT + (((size_t)s * B_SZ + b) * I_SZ + i)) = hv;
}

// Wenc[r][0:256]=eWih[r], [256:768]=eWhh[r]  (fp16)
__global__ void k_wenc(const float* __restrict__ eWih, const float* __restrict__ eWhh,
                       _Float16* __restrict__ Wenc) {
    int idx = blockIdx.x * blockDim.x + threadIdx.x;
    int r = idx / 768, col = idx % 768;
    float v = (col < 256) ? eWih[(size_t)r * 256 + col] : eWhh[(size_t)r * 512 + col - 256];
    Wenc[idx] = (_Float16)v;
}

// Wd[r,k] = dWhh[r,k] + sum_o dWih[r,o] * fcW[o,k]
__global__ __launch_bounds__(256) void k_wd(
    const float* __restrict__ dWhh, const float* __restrict__ dWih,
    const float* __restrict__ fcW, _Float16* __restrict__ Wd)
{
    __shared__ float sA[8][256];
    const int tid = threadIdx.x;
    const int r0 = blockIdx.x * 8;
    {
        int linear = tid * 8;
        int row = linear >> 8, col = linear & 255;
        const float4* p = (const float4*)(dWih + (size_t)(r0 + row) * 256 + col);
        float4 v0 = p[0], v1 = p[1];
        *(float4*)&sA[row][col]     = v0;
        *(float4*)&sA[row][col + 4] = v1;
    }
    __syncthreads();
    float acc[8][2] = {};
    const int k = tid;
    for (int i = 0; i < 256; ++i) {
        float w0 = fcW[(size_t)i * 512 + k];
        float w1 = fcW[(size_t)i * 512 + k + 256];
        #pragma unroll
        for (int rr = 0; rr < 8; ++rr) {
            float a = sA[rr][i];
            acc[rr][0] += a * w0;
            acc[rr][1] += a * w1;
        }
    }
    #pragma unroll
    for (int rr = 0; rr < 8; ++rr) {
        size_t base = (size_t)(r0 + rr) * 512;
        Wd[base + k]       = (_Float16)(dWhh[base + k]       + acc[rr][0]);
        Wd[base + k + 256] = (_Float16)(dWhh[base + k + 256] + acc[rr][1]);
    }
}

// ---------------- persistent whole-recurrence kernel ----------------
// EXACT round-11 chain (best validated: 1167 us): GLDS staging, 2-buf double
// buffer, counted vmcnt(8), 2 barriers/iter, unique h slab per step, sc
// write-through h stores, relaxed group counters, 2-D XCD placement
// (8 mb x 8 jb per XCD -> W slice L2-resident). No setprio, no prestage.
__global__ __launch_bounds__(256, 2) void k_lstm_all(
    const _Float16* __restrict__ xT,     // [S][B][256] fp16
    const _Float16* __restrict__ Wenc,   // [2048][768]
    const _Float16* __restrict__ dWhh_h, // [2048][512]
    const _Float16* __restrict__ Wd,     // [2048][512]
    const float* __restrict__ eb, const float* __restrict__ db,
    const float* __restrict__ bd,
    _Float16* __restrict__ henc,         // [49][B][512] unique slabs
    _Float16* __restrict__ hseq,         // [21][B][512]
    unsigned* __restrict__ bar)          // 32 counters, 16 uints apart
{
    __shared__ _Float16 lds[2][2][128 * 64];   // 64 KB

    const int tid = threadIdx.x;
    const int xcd = blockIdx.x & 7, slot = blockIdx.x >> 3;
    const int mb = (xcd >> 1) * 8 + (slot >> 3);
    const int jb = (xcd & 1) * 8 + (slot & 7);
    const int m0 = mb * 128, j0 = jb * 32;
    unsigned* grp = bar + mb * 16;

    const int wv = tid >> 6, lane = tid & 63, lrow = lane & 15, lk8 = (lane >> 4) * 8;
    const int wm = wv >> 1, wn = wv & 1;

    // ---- staging geometry: precomputed per-q pointers ----
    const int colb  = (lane & 7) * 16;
    const int scolh = (colb ^ (((lane >> 3) & 7) << 4)) >> 1;
    const _Float16* wEncQ[4]; const _Float16* wD0Q[4]; const _Float16* wDQ[4];
    const _Float16* xQ[4];
    unsigned aOffQ[4];
    int ldsQ[4];
    #pragma unroll
    for (int q = 0; q < 4; ++q) {
        int r = q * 32 + wv * 8 + (lane >> 3);
        int grow = ((r >> 4) & 3) * H_SZ + j0 + (r >> 6) * 16 + (r & 15);
        wEncQ[q] = Wenc   + (size_t)grow * 768 + scolh;
        wD0Q[q]  = dWhh_h + (size_t)grow * 512 + scolh;
        wDQ[q]   = Wd     + (size_t)grow * 512 + scolh;
        xQ[q]    = xT + (size_t)(m0 + r) * I_SZ + scolh;
        aOffQ[q] = (unsigned)((m0 + r) * H_SZ) + scolh;
        ldsQ[q]  = (q * 256 + wv * 64) * 8;
    }

    float ebj[4], dbj[4], bdj[4];
    #pragma unroll
    for (int nf = 0; nf < 4; ++nf) {
        int col = nf * H_SZ + j0 + wn * 16 + lrow;
        ebj[nf] = eb[col]; dbj[nf] = db[col]; bdj[nf] = bd[col];
    }

    float creg[4][4];

    auto wait_group = [&](unsigned target) {
        MEMFENCE;
        if (tid == 0) {
            while (__hip_atomic_load(grp, __ATOMIC_RELAXED, __HIP_MEMORY_SCOPE_AGENT) < target)
                __builtin_amdgcn_s_sleep(1);
        }
        __builtin_amdgcn_s_barrier();
        MEMFENCE;
    };
    auto arrive = [&]() {
        __syncthreads();   // drains h sc-stores (vmcnt 0) before signaling
        if (tid == 0)
            __hip_atomic_fetch_add(grp, 1u, __ATOMIC_RELAXED, __HIP_MEMORY_SCOPE_AGENT);
    };

    auto compute = [&](int buf, f32x4 (&acc)[4][4]) {
        #pragma unroll
        for (int kc = 0; kc < 2; ++kc) {
            const int sc = (((kc * 32 + lk8) * 2) ^ ((lrow & 7) << 4)) >> 1;
            half8 a[4], b[4];
            #pragma unroll
            for (int mf = 0; mf < 4; ++mf)
                a[mf] = *(const half8*)&lds[buf][0][(wm * 64 + mf * 16 + lrow) * 64 + sc];
            #pragma unroll
            for (int nf = 0; nf < 4; ++nf)
                b[nf] = *(const half8*)&lds[buf][1][(wn * 64 + nf * 16 + lrow) * 64 + sc];
            #pragma unroll
            for (int mf = 0; mf < 4; ++mf)
                #pragma unroll
                for (int nf = 0; nf < 4; ++nf)
                    acc[mf][nf] = __builtin_amdgcn_mfma_f32_16x16x32_f16(a[mf], b[nf], acc[mf][nf], 0, 0, 0);
        }
    };

    auto epilogue = [&](f32x4 (&acc)[4][4], const float (&bj)[4], _Float16* hout, bool first) {
        _Float16* hsm = &lds[0][0][0];
        const int lc = wn * 16 + lrow;
        #pragma unroll
        for (int mf = 0; mf < 4; ++mf)
            #pragma unroll
            for (int r = 0; r < 4; ++r) {
                int lr = wm * 64 + mf * 16 + (lane >> 4) * 4 + r;
                float gi = acc[mf][0][r] + bj[0];
                float gf = acc[mf][1][r] + bj[1];
                float gg = acc[mf][2][r] + bj[2];
                float go = acc[mf][3][r] + bj[3];
                float cold = first ? 0.0f : creg[mf][r];
                float cn = sigm(gf) * cold + sigm(gi) * tanh_fast(gg);
                creg[mf][r] = cn;
                hsm[lr * PAD_H + lc] = (_Float16)(sigm(go) * tanh_fast(cn));
            }
        __syncthreads();
        int rr = tid >> 3, k = tid & 7;
        #pragma unroll
        for (int q = 0; q < 4; ++q) {
            int r = rr + q * 32;
            unsigned long long v = *(const unsigned long long*)&hsm[r * PAD_H + k * 4];
            unsigned long long* dst =
                (unsigned long long*)(hout + (size_t)(m0 + r) * H_SZ + j0) + k;
            __hip_atomic_store(dst, v, __ATOMIC_RELAXED, __HIP_MEMORY_SCOPE_AGENT);
        }
    };

    // ================= phase A: encoder step 0 (x only, 4 tiles) =================
    {
        f32x4 acc[4][4] = {};
        #pragma unroll
        for (int q = 0; q < 4; ++q) { GLDS(xQ[q], &lds[0][0][ldsQ[q]]); GLDS(wEncQ[q], &lds[0][1][ldsQ[q]]); }
        #pragma unroll
        for (int it = 0; it < 4; ++it) {
            if (it < 3) {
                #pragma unroll
                for (int q = 0; q < 4; ++q) {
                    GLDS(xQ[q] + (it + 1) * 64, &lds[(it + 1) & 1][0][ldsQ[q]]);
                    GLDS(wEncQ[q] + (it + 1) * 64, &lds[(it + 1) & 1][1][ldsQ[q]]);
                }
                asm volatile("s_waitcnt vmcnt(8)" ::: "memory");
            } else {
                asm volatile("s_waitcnt vmcnt(0)" ::: "memory");
            }
            __builtin_amdgcn_s_barrier(); MEMFENCE;
            compute(it & 1, acc);
            MEMFENCE; __builtin_amdgcn_s_barrier(); MEMFENCE;
        }
        epilogue(acc, ebj, henc, true);
        arrive();
    }

    // ================= phase B: encoder steps 1..49 (12 tiles) =================
    for (int s = 1; s < S_SZ; ++s) {
        const size_t xoff = (size_t)s * B_SZ * I_SZ;
        const _Float16* hin = henc + (size_t)(s - 1) * BH;
        _Float16* hout = (s == S_SZ - 1) ? hseq : henc + (size_t)s * BH;
        f32x4 acc[4][4] = {};
        #pragma unroll
        for (int q = 0; q < 4; ++q) { GLDS(xQ[q] + xoff, &lds[0][0][ldsQ[q]]); GLDS(wEncQ[q], &lds[0][1][ldsQ[q]]); }
        #pragma unroll
        for (int it = 0; it < 12; ++it) {
            if (it < 11) {
                if (it == 3) wait_group((unsigned)s * 16u);
                #pragma unroll
                for (int q = 0; q < 4; ++q) {
                    if (it + 1 < 4) GLDS(xQ[q] + xoff + (it + 1) * 64, &lds[(it + 1) & 1][0][ldsQ[q]]);
                    else            GLDS(hin + aOffQ[q] + (it - 3) * 64, &lds[(it + 1) & 1][0][ldsQ[q]]);
                    GLDS(wEncQ[q] + (it + 1) * 64, &lds[(it + 1) & 1][1][ldsQ[q]]);
                }
                asm volatile("s_waitcnt vmcnt(8)" ::: "memory");
            } else {
                asm volatile("s_waitcnt vmcnt(0)" ::: "memory");
            }
            __builtin_amdgcn_s_barrier(); MEMFENCE;
            compute(it & 1, acc);
            MEMFENCE; __builtin_amdgcn_s_barrier(); MEMFENCE;
        }
        epilogue(acc, ebj, hout, false);
        arrive();
    }

    // ================= phase C: decoder steps 0..19 (8 tiles) =================
    for (int t = 0; t < T_SZ; ++t) {
        const _Float16* hin = hseq + (size_t)t * BH;
        _Float16* hout = hseq + (size_t)(t + 1) * BH;
        const _Float16* wq[4];
        float bj[4];
        #pragma unroll
        for (int q = 0; q < 4; ++q) wq[q] = t ? wDQ[q] : wD0Q[q];
        #pragma unroll
        for (int nf = 0; nf < 4; ++nf) bj[nf] = t ? bdj[nf] : dbj[nf];

        wait_group((unsigned)(S_SZ + t) * 16u);
        f32x4 acc[4][4] = {};
        #pragma unroll
        for (int q = 0; q < 4; ++q) { GLDS(hin + aOffQ[q], &lds[0][0][ldsQ[q]]); GLDS(wq[q], &lds[0][1][ldsQ[q]]); }
        #pragma unroll
        for (int it = 0; it < 8; ++it) {
            if (it < 7) {
                #pragma unroll
                for (int q = 0; q < 4; ++q) {
                    GLDS(hin + aOffQ[q] + (it + 1) * 64, &lds[(it + 1) & 1][0][ldsQ[q]]);
                    GLDS(wq[q] + (it + 1) * 64, &lds[(it + 1) & 1][1][ldsQ[q]]);
                }
                asm volatile("s_waitcnt vmcnt(8)" ::: "memory");
            } else {
                asm volatile("s_waitcnt vmcnt(0)" ::: "memory");
            }
            __builtin_amdgcn_s_barrier(); MEMFENCE;
            compute(it & 1, acc);
            MEMFENCE; __builtin_amdgcn_s_barrier(); MEMFENCE;
        }
        epilogue(acc, bj, hout, false);
        if (t != T_SZ - 1) arrive();
    }
}

// ---------------- batched final FC over all decoder h's ----------------
__global__ __launch_bounds__(256) void k_fc(
    const _Float16* __restrict__ hseq1,  // [T][B][512]
    const _Float16* __restrict__ W,      // fcW fp16 [256][512]
    const float* __restrict__ bias,      // [256]
    float* __restrict__ out)
{
    __shared__ _Float16 Asm[128][PAD];
    __shared__ _Float16 Bsm[128][PAD];

    const int tid = threadIdx.x;
    const int m0 = blockIdx.x * 128;
    const int t  = blockIdx.y;
    const int n0 = blockIdx.z * 128;
    const int wv = tid >> 6, lane = tid & 63, lrow = lane & 15, lk = (lane >> 4) * 8;
    const int wm = wv >> 1, wn = wv & 1;

    f32x4 acc[4][4] = {};

    const int srow = tid >> 3, skc = (tid & 7) * 8;
    const _Float16* A = hseq1 + (size_t)t * BH;

    for (int k0 = 0; k0 < H_SZ; k0 += 64) {
        __syncthreads();
        #pragma unroll
        for (int q = 0; q < 4; ++q) {
            int r = srow + q * 32;
            *(half8*)&Asm[r][skc] = *(const half8*)(A + (size_t)(m0 + r) * H_SZ + k0 + skc);
        }
        #pragma unroll
        for (int q = 0; q < 4; ++q) {
            int rr = srow + q * 32;
            *(half8*)&Bsm[rr][skc] = *(const half8*)(W + (size_t)(n0 + rr) * H_SZ + k0 + skc);
        }
        __syncthreads();
        #pragma unroll
        for (int kc = 0; kc < 64; kc += 32) {
            half8 a[4], b[4];
            #pragma unroll
            for (int mf = 0; mf < 4; ++mf) a[mf] = *(const half8*)&Asm[wm * 64 + mf * 16 + lrow][kc + lk];
            #pragma unroll
            for (int nf = 0; nf < 4; ++nf) b[nf] = *(const half8*)&Bsm[wn * 64 + nf * 16 + lrow][kc + lk];
            #pragma unroll
            for (int mf = 0; mf < 4; ++mf)
                #pragma unroll
                for (int nf = 0; nf < 4; ++nf)
                    acc[mf][nf] = __builtin_amdgcn_mfma_f32_16x16x32_f16(a[mf], b[nf], acc[mf][nf], 0, 0, 0);
        }
    }

    #pragma unroll
    for (int mf = 0; mf < 4; ++mf)
        #pragma unroll
        for (int nf = 0; nf < 4; ++nf) {
            int o = n0 + wn * 64 + nf * 16 + lrow;
            float bv = bias[o];
            #pragma unroll
            for (int r = 0; r < 4; ++r) {
                int m = m0 + wm * 64 + mf * 16 + (lane >> 4) * 4 + r;
                out[(size_t)m * (T_SZ * O_SZ) + (size_t)t * O_SZ + o] = acc[mf][nf][r] + bv;
            }
        }
}

extern "C" void kernel_launch(void* const* d_in, const int* in_sizes, int n_in,
                              void* d_out, int out_size, void* d_ws, size_t ws_size,
                              hipStream_t stream) {
    (void)in_sizes; (void)n_in; (void)out_size; (void)ws_size;

    const float* x    = (const float*)d_in[0];
    const float* eWih = (const float*)d_in[1];
    const float* eWhh = (const float*)d_in[2];
    const float* ebih = (const float*)d_in[3];
    const float* ebhh = (const float*)d_in[4];
    const float* dWih = (const float*)d_in[5];
    const float* dWhh = (const float*)d_in[6];
    const float* dbih = (const float*)d_in[7];
    const float* dbhh = (const float*)d_in[8];
    const float* fcW  = (const float*)d_in[9];
    const float* fcb  = (const float*)d_in[10];
    float* out = (float*)d_out;
    char* ws = (char*)d_ws;

    size_t off = 0;
    auto alloc = [&](size_t bytes) -> void* {
        void* p = ws + off;
        off += (bytes + 255) & ~(size_t)255;
        return p;
    };
    _Float16* xT     = (_Float16*)alloc((size_t)S_SZ * B_SZ * I_SZ * 2);
    _Float16* Wenc   = (_Float16*)alloc((size_t)G4H * (I_SZ + H_SZ) * 2);
    _Float16* dWhh_h = (_Float16*)alloc((size_t)G4H * H_SZ * 2);
    _Float16* Wd     = (_Float16*)alloc((size_t)G4H * H_SZ * 2);
    _Float16* fcW_h  = (_Float16*)alloc((size_t)O_SZ * H_SZ * 2);
    float*    eb     = (float*)alloc(G4H * 4);
    float*    db     = (float*)alloc(G4H * 4);
    float*    bd     = (float*)alloc(G4H * 4);
    _Float16* henc   = (_Float16*)alloc((size_t)(S_SZ - 1) * BH * 2);   // 49 slabs
    _Float16* hseq   = (_Float16*)alloc((size_t)(T_SZ + 1) * BH * 2);   // 21 slabs
    unsigned* bar    = (unsigned*)alloc(32 * 16 * 4);

    const int nWhh = G4H * H_SZ;
    const size_t nX = (size_t)B_SZ * S_SZ * I_SZ;

    k_prep_small<<<8 + (O_SZ * H_SZ + 255) / 256, 256, 0, stream>>>(
        bar, ebih, ebhh, dbih, dbhh, dWih, fcb, fcW, eb, db, bd, fcW_h);
    k_cvt_x<<<(int)(nX / 8 / 256), 256, 0, stream>>>(x, xT);
    k_wenc<<<(G4H * 768) / 256, 256, 0, stream>>>(eWih, eWhh, Wenc);
    k_cvt<<<(nWhh + 255) / 256, 256, 0, stream>>>(dWhh, dWhh_h, nWhh);
    k_wd<<<256, 256, 0, stream>>>(dWhh, dWih, fcW, Wd);

    k_lstm_all<<<NB, 256, 0, stream>>>(xT, Wenc, dWhh_h, Wd, eb, db, bd,
                                       henc, hseq, bar);

    k_fc<<<dim3(B_SZ / 128, T_SZ, O_SZ / 128), 256, 0, stream>>>(
        hseq + BH, fcW_h, fcb, out);
}